// Round 3
// baseline (290.088 us; speedup 1.0000x reference)
//
#include <hip/hip_runtime.h>
#include <hip/hip_bf16.h>

// sinogram: [1,16,360,736] f32, grid: [1,360,16384,2] f32,
// square_inv: [1,1,360,16384] f32, out: [1,16,16384] f32
#define NP 16384
#define NV 360
#define ND 736
#define NC 16
#define VSPLIT 32
#define QSZ (NV * ND * 8)   // ushort elems per 8-channel half-table (4.25 MB)

// Pass 1: transpose + quantize sinogram [C][H*W] -> two bf16 half-tables
// [half][y][x][8ch]. One corner's 8 channels = 16 aligned bytes (1 dwordx4).
__global__ __launch_bounds__(256) void sino_transpose_bf16(const float* __restrict__ sino,
                                                           ushort* __restrict__ st) {
    int idx = blockIdx.x * 256 + threadIdx.x;   // idx = y*ND + x
    if (idx >= NV * ND) return;
    uint packed[8];
#pragma unroll
    for (int q = 0; q < 8; ++q) {
        uint ul = __float_as_uint(sino[(2 * q)     * (NV * ND) + idx]);
        uint uh = __float_as_uint(sino[(2 * q + 1) * (NV * ND) + idx]);
        // round-to-nearest-even bf16
        ul = (ul + 0x7fffu + ((ul >> 16) & 1u)) >> 16;
        uh = (uh + 0x7fffu + ((uh >> 16) & 1u)) >> 16;
        packed[q] = ul | (uh << 16);
    }
    uint4* d0 = reinterpret_cast<uint4*>(st + ((size_t)idx << 3));
    uint4* d1 = reinterpret_cast<uint4*>(st + QSZ + ((size_t)idx << 3));
    *d0 = make_uint4(packed[0], packed[1], packed[2], packed[3]);
    *d1 = make_uint4(packed[4], packed[5], packed[6], packed[7]);
}

// Pass 2: thread = (channel-half Q, pixel p, view-chunk vs). 8 fp32 register
// accumulators; one atomicAdd per channel at the end.
// Q = blockIdx&1 so (by round-robin block->XCD dispatch) even XCDs only touch
// half 0 and odd XCDs half 1: 4.25 MB gather set ~= per-XCD L2.
__global__ __launch_bounds__(256) void backproj(const float* __restrict__ grd,
                                                const float* __restrict__ sq,
                                                const ushort* __restrict__ st,
                                                float* __restrict__ out) {
    int Q    = blockIdx.x & 1;
    int r    = blockIdx.x >> 1;
    int pblk = r & 63;            // 16384/256 p-blocks
    int vs   = r >> 6;
    int p  = pblk * 256 + threadIdx.x;
    int v0 = (vs * NV) / VSPLIT;          // balanced 11/12-view chunks
    int v1 = ((vs + 1) * NV) / VSPLIT;

    const ushort* __restrict__ tbl = st + Q * QSZ;

    float acc[8];
#pragma unroll
    for (int c = 0; c < 8; ++c) acc[c] = 0.0f;

    const float2* grd2 = reinterpret_cast<const float2*>(grd);

    auto gather = [&](int idx, float w) {
        uint4 a = *reinterpret_cast<const uint4*>(tbl + ((size_t)idx << 3));
        uint u[4] = {a.x, a.y, a.z, a.w};
#pragma unroll
        for (int q = 0; q < 4; ++q) {
            acc[2 * q]     = fmaf(__uint_as_float(u[q] << 16),         w, acc[2 * q]);
            acc[2 * q + 1] = fmaf(__uint_as_float(u[q] & 0xffff0000u), w, acc[2 * q + 1]);
        }
    };

#pragma unroll 2
    for (int v = v0; v < v1; ++v) {
        int gi = v * NP + p;
        float2 g = grd2[gi];                 // coalesced 8B/lane
        float w  = sq[gi] * 1000.0f;         // coalesced 4B/lane

        // unnormalize, align_corners=False (exact reference formula)
        float ix = ((g.x + 1.0f) * (float)ND - 1.0f) * 0.5f;
        float iy = ((g.y + 1.0f) * (float)NV - 1.0f) * 0.5f;
        float x0f = floorf(ix), y0f = floorf(iy);
        float wx = ix - x0f,   wy = iy - y0f;    // weights from UNclamped floor
        int x0i = (int)x0f, y0i = (int)y0f;
        int x0 = min(max(x0i,     0), ND - 1);
        int x1 = min(max(x0i + 1, 0), ND - 1);
        int y0 = min(max(y0i,     0), NV - 1);
        int y1 = min(max(y0i + 1, 0), NV - 1);

        float w00 = (1.0f - wx) * (1.0f - wy) * w;
        float w01 = wx * (1.0f - wy) * w;
        float w10 = (1.0f - wx) * wy * w;
        float w11 = wx * wy * w;

        gather(y0 * ND + x0, w00);
        gather(y0 * ND + x1, w01);
        gather(y1 * ND + x0, w10);
        gather(y1 * ND + x1, w11);
    }

#pragma unroll
    for (int c = 0; c < 8; ++c)
        atomicAdd(&out[(Q * 8 + c) * NP + p], acc[c]);   // 32 contenders/loc
}

extern "C" void kernel_launch(void* const* d_in, const int* in_sizes, int n_in,
                              void* d_out, int out_size, void* d_ws, size_t ws_size,
                              hipStream_t stream) {
    const float* sino = (const float*)d_in[0];
    const float* grd  = (const float*)d_in[1];
    const float* sq   = (const float*)d_in[2];
    float* out = (float*)d_out;
    ushort* st = (ushort*)d_ws;           // 2 * 4.25 MB

    hipMemsetAsync(out, 0, (size_t)out_size * sizeof(float), stream);

    {
        int n = NV * ND;
        sino_transpose_bf16<<<(n + 255) / 256, 256, 0, stream>>>(sino, st);
    }
    {
        int nblocks = 2 * 64 * VSPLIT;    // Q x pblk x vs = 4096 blocks
        backproj<<<nblocks, 256, 0, stream>>>(grd, sq, st, out);
    }
}

// Round 5
// 248.099 us; speedup vs baseline: 1.1692x; 1.1692x over previous
//
#include <hip/hip_runtime.h>
#include <hip/hip_bf16.h>

// sinogram: [1,16,360,736] f32, grid: [1,360,16384,2] f32,
// square_inv: [1,1,360,16384] f32, out: [1,16,16384] f32
#define NP 16384
#define NV 360
#define ND 736
#define NC 16
#define VS 16               // view chunks
#define QSZ (NV * ND * 8)   // ushort elems per 8-channel half-table (4.25 MB)

// Pass 1: transpose + quantize sinogram [C][H*W] -> two bf16 half-tables
// [half][y][x][8ch]. One corner's 8 channels = 16 aligned bytes.
__global__ __launch_bounds__(256) void sino_transpose_bf16(const float* __restrict__ sino,
                                                           ushort* __restrict__ st) {
    int idx = blockIdx.x * 256 + threadIdx.x;   // idx = y*ND + x
    if (idx >= NV * ND) return;
    uint packed[8];
#pragma unroll
    for (int q = 0; q < 8; ++q) {
        uint ul = __float_as_uint(sino[(2 * q)     * (NV * ND) + idx]);
        uint uh = __float_as_uint(sino[(2 * q + 1) * (NV * ND) + idx]);
        // round-to-nearest-even bf16
        ul = (ul + 0x7fffu + ((ul >> 16) & 1u)) >> 16;
        uh = (uh + 0x7fffu + ((uh >> 16) & 1u)) >> 16;
        packed[q] = ul | (uh << 16);
    }
    uint4* d0 = reinterpret_cast<uint4*>(st + ((size_t)idx << 3));
    uint4* d1 = reinterpret_cast<uint4*>(st + QSZ + ((size_t)idx << 3));
    *d0 = make_uint4(packed[0], packed[1], packed[2], packed[3]);
    *d1 = make_uint4(packed[4], packed[5], packed[6], packed[7]);
}

// Pass 2: lane PAIRS (2i,2i+1) own one pixel; even lane gathers the x0 side,
// odd lane the x1 side (adjacent 16B blocks -> usually the same 64B line, to
// test TA same-line lane merging). Q = blockIdx&1 keeps the XCD channel
// affinity that pinned FETCH at ~237MB.
__global__ __launch_bounds__(256) void backproj(const float* __restrict__ grd,
                                                const float* __restrict__ sq,
                                                const ushort* __restrict__ st,
                                                float* __restrict__ out) {
    int Q    = blockIdx.x & 1;
    int r    = blockIdx.x >> 1;
    int pblk = r & 127;                  // 16384/128 pixel-pairs per block
    int vs   = r >> 7;
    int pr   = threadIdx.x >> 1;         // pair index 0..127
    int c    = threadIdx.x & 1;          // 0: x0 side, 1: x1 side
    int p    = pblk * 128 + pr;
    int v0 = (vs * NV) / VS;
    int v1 = ((vs + 1) * NV) / VS;

    const ushort* __restrict__ tbl = st + Q * QSZ;

    float acc[8];
#pragma unroll
    for (int k = 0; k < 8; ++k) acc[k] = 0.0f;

    const float2* grd2 = reinterpret_cast<const float2*>(grd);

    auto gather = [&](int idx, float w) {
        uint4 a = *reinterpret_cast<const uint4*>(tbl + ((size_t)idx << 3));
        uint u[4] = {a.x, a.y, a.z, a.w};
#pragma unroll
        for (int q = 0; q < 4; ++q) {
            acc[2 * q]     = fmaf(__uint_as_float(u[q] << 16),         w, acc[2 * q]);
            acc[2 * q + 1] = fmaf(__uint_as_float(u[q] & 0xffff0000u), w, acc[2 * q + 1]);
        }
    };

#pragma unroll 2
    for (int v = v0; v < v1; ++v) {
        int gi = v * NP + p;
        float2 g = grd2[gi];                 // pairs read duplicate addrs, coalesced
        float w  = sq[gi] * 1000.0f;

        // unnormalize, align_corners=False (exact reference formula)
        float ix = ((g.x + 1.0f) * (float)ND - 1.0f) * 0.5f;
        float iy = ((g.y + 1.0f) * (float)NV - 1.0f) * 0.5f;
        float x0f = floorf(ix), y0f = floorf(iy);
        float wx = ix - x0f,   wy = iy - y0f;    // weights from UNclamped floor
        int x0i = (int)x0f, y0i = (int)y0f;
        int x0 = min(max(x0i,     0), ND - 1);
        int x1 = min(max(x0i + 1, 0), ND - 1);
        int y0 = min(max(y0i,     0), NV - 1);
        int y1 = min(max(y0i + 1, 0), NV - 1);

        int   xc  = c ? x1 : x0;             // my side of the pair
        float wxc = (c ? wx : (1.0f - wx)) * w;

        gather(y0 * ND + xc, wxc * (1.0f - wy));   // row y0 (pair shares line)
        gather(y1 * ND + xc, wxc * wy);            // row y1 (pair shares line)
    }

    // combine the pair, then one atomic per channel from the even lane
#pragma unroll
    for (int k = 0; k < 8; ++k) acc[k] += __shfl_xor(acc[k], 1);
    if (c == 0) {
#pragma unroll
        for (int k = 0; k < 8; ++k)
            atomicAdd(&out[(Q * 8 + k) * NP + p], acc[k]);
    }
}

extern "C" void kernel_launch(void* const* d_in, const int* in_sizes, int n_in,
                              void* d_out, int out_size, void* d_ws, size_t ws_size,
                              hipStream_t stream) {
    const float* sino = (const float*)d_in[0];
    const float* grd  = (const float*)d_in[1];
    const float* sq   = (const float*)d_in[2];
    float* out = (float*)d_out;
    ushort* st = (ushort*)d_ws;           // 2 * 4.25 MB

    hipMemsetAsync(out, 0, (size_t)out_size * sizeof(float), stream);

    {
        int n = NV * ND;
        sino_transpose_bf16<<<(n + 255) / 256, 256, 0, stream>>>(sino, st);
    }
    {
        int nblocks = 2 * 128 * VS;       // Q x pblk x vs = 4096 blocks
        backproj<<<nblocks, 256, 0, stream>>>(grd, sq, st, out);
    }
}

// Round 6
// 243.417 us; speedup vs baseline: 1.1917x; 1.0192x over previous
//
#include <hip/hip_runtime.h>
#include <hip/hip_bf16.h>

// sinogram: [1,16,360,736] f32, grid: [1,360,16384,2] f32,
// square_inv: [1,1,360,16384] f32, out: [1,16,16384] f32
#define NP 16384
#define NV 360
#define ND 736
#define NC 16
#define VS 16               // view chunks
#define QSZ (NV * ND * 8)   // ushort elems per 8-channel half-table (4.25 MB)

// Pass 1: transpose + quantize sinogram [C][H*W] -> two bf16 half-tables
// [half][y][x][8ch]; ALSO zero d_out (fused, replaces hipMemsetAsync node).
__global__ __launch_bounds__(256) void sino_transpose_bf16(const float* __restrict__ sino,
                                                           ushort* __restrict__ st,
                                                           float* __restrict__ out) {
    int idx = blockIdx.x * 256 + threadIdx.x;   // idx = y*ND + x
    if (idx < NC * NP) out[idx] = 0.0f;         // 262144 <= 264960 threads
    if (idx >= NV * ND) return;
    uint packed[8];
#pragma unroll
    for (int q = 0; q < 8; ++q) {
        uint ul = __float_as_uint(sino[(2 * q)     * (NV * ND) + idx]);
        uint uh = __float_as_uint(sino[(2 * q + 1) * (NV * ND) + idx]);
        // round-to-nearest-even bf16
        ul = (ul + 0x7fffu + ((ul >> 16) & 1u)) >> 16;
        uh = (uh + 0x7fffu + ((uh >> 16) & 1u)) >> 16;
        packed[q] = ul | (uh << 16);
    }
    uint4* d0 = reinterpret_cast<uint4*>(st + ((size_t)idx << 3));
    uint4* d1 = reinterpret_cast<uint4*>(st + QSZ + ((size_t)idx << 3));
    *d0 = make_uint4(packed[0], packed[1], packed[2], packed[3]);
    *d1 = make_uint4(packed[4], packed[5], packed[6], packed[7]);
}

// Pass 2: lane PAIRS (2i,2i+1) own one pixel. Even lane gathers x0 side, odd
// lane x1 side. Stream loads deduped: lane0 loads grid float2, lane1 loads the
// aligned float2 covering sq[gi]; 2 shfl_xor exchange. Q=blockIdx&1 keeps XCD
// L2 channel affinity (FETCH ~237MB).
__global__ __launch_bounds__(256) void backproj(const float* __restrict__ grd,
                                                const float* __restrict__ sq,
                                                const ushort* __restrict__ st,
                                                float* __restrict__ out) {
    int Q    = blockIdx.x & 1;
    int r    = blockIdx.x >> 1;
    int pblk = r & 127;                  // 128 pixel-pairs per block
    int vs   = r >> 7;
    int pr   = threadIdx.x >> 1;         // pair index 0..127
    int c    = threadIdx.x & 1;          // 0: x0 side, 1: x1 side
    int p    = pblk * 128 + pr;
    int v0 = (vs * NV) / VS;
    int v1 = ((vs + 1) * NV) / VS;

    const ushort* __restrict__ tbl = st + Q * QSZ;

    float acc[8];
#pragma unroll
    for (int k = 0; k < 8; ++k) acc[k] = 0.0f;

    const float2* grd2 = reinterpret_cast<const float2*>(grd);
    int podd = p & 1;                    // sq[gi] parity (gi = v*NP+p, NP even)

    auto gather = [&](int idx, float w) {
        uint4 a = *reinterpret_cast<const uint4*>(tbl + ((size_t)idx << 3));
        uint u[4] = {a.x, a.y, a.z, a.w};
#pragma unroll
        for (int q = 0; q < 4; ++q) {
            acc[2 * q]     = fmaf(__uint_as_float(u[q] << 16),         w, acc[2 * q]);
            acc[2 * q + 1] = fmaf(__uint_as_float(u[q] & 0xffff0000u), w, acc[2 * q + 1]);
        }
    };

#pragma unroll 4
    for (int v = v0; v < v1; ++v) {
        int gi = v * NP + p;
        // one dwordx2 per lane: lane0 -> grid pair, lane1 -> sq aligned pair
        const float2* addr = (c == 0)
            ? (grd2 + gi)
            : reinterpret_cast<const float2*>(sq + (gi & ~1));
        float2 val = *addr;
        float r0 = __shfl_xor(val.x, 1);
        float r1 = __shfl_xor(val.y, 1);
        float gx, gy, w;
        if (c == 0) { gx = val.x; gy = val.y; w = podd ? r1 : r0; }
        else        { gx = r0;    gy = r1;    w = podd ? val.y : val.x; }
        w *= 1000.0f;

        // unnormalize, align_corners=False (exact reference formula)
        float ix = ((gx + 1.0f) * (float)ND - 1.0f) * 0.5f;
        float iy = ((gy + 1.0f) * (float)NV - 1.0f) * 0.5f;
        float x0f = floorf(ix), y0f = floorf(iy);
        float wx = ix - x0f,   wy = iy - y0f;    // weights from UNclamped floor
        int x0i = (int)x0f, y0i = (int)y0f;
        int x0 = min(max(x0i,     0), ND - 1);
        int x1 = min(max(x0i + 1, 0), ND - 1);
        int y0 = min(max(y0i,     0), NV - 1);
        int y1 = min(max(y0i + 1, 0), NV - 1);

        int   xc  = c ? x1 : x0;             // my side of the pair
        float wxc = (c ? wx : (1.0f - wx)) * w;

        gather(y0 * ND + xc, wxc * (1.0f - wy));   // row y0 (pair shares line)
        gather(y1 * ND + xc, wxc * wy);            // row y1 (pair shares line)
    }

    // combine the pair, then one atomic per channel from the even lane
#pragma unroll
    for (int k = 0; k < 8; ++k) acc[k] += __shfl_xor(acc[k], 1);
    if (c == 0) {
#pragma unroll
        for (int k = 0; k < 8; ++k)
            atomicAdd(&out[(Q * 8 + k) * NP + p], acc[k]);
    }
}

extern "C" void kernel_launch(void* const* d_in, const int* in_sizes, int n_in,
                              void* d_out, int out_size, void* d_ws, size_t ws_size,
                              hipStream_t stream) {
    const float* sino = (const float*)d_in[0];
    const float* grd  = (const float*)d_in[1];
    const float* sq   = (const float*)d_in[2];
    float* out = (float*)d_out;
    ushort* st = (ushort*)d_ws;           // 2 * 4.25 MB

    {
        int n = NV * ND;                  // also covers NC*NP out-zeroing
        sino_transpose_bf16<<<(n + 255) / 256, 256, 0, stream>>>(sino, st, out);
    }
    {
        int nblocks = 2 * 128 * VS;       // Q x pblk x vs = 4096 blocks
        backproj<<<nblocks, 256, 0, stream>>>(grd, sq, st, out);
    }
}